// Round 4
// baseline (22.610 us; speedup 1.0000x reference)
//
#include <hip/hip_runtime.h>

// PadMaskedSequence, single fused kernel, one block per (batch, chunk-of-64-rows).
// d_out layout: x_ [B*T*D] f32, then lens [B] as float.
//
// Each block independently: (1) reads the L2-resident mask row once, reducing
// BOTH prefix-popcount P = sum(mask[0:c*64)) and total L = sum(mask[0:T)) in
// one packed 64-bit shuffle reduction; (2) wave 0 compacts the chunk's
// selected rows into an LDS list; (3) all waves copy the listed rows to
// output rows P+i (unconditional, 2-unrolled for ILP); (4) zero-pads output
// rows [max(j0,L), j0+64) of its own range. Every output row written exactly
// once; no inter-block communication.

#define BLK 256
#define NW (BLK / 64)
#define ROWS 64

__global__ __launch_bounds__(BLK) void pad_masked_fused(
    const float* __restrict__ x,
    const int* __restrict__ mask,
    float* __restrict__ out,
    float* __restrict__ lens_f,
    int T, int D4) {

    const int c = blockIdx.x;
    const int b = blockIdx.y;
    const int tid = threadIdx.x;
    const int lane = tid & 63;
    const int wave = tid >> 6;
    const int j0 = c * ROWS;

    const int* mrow = mask + (size_t)b * T;

    // ---- packed popcount: pre = [0, j0), all = [0, T) ----
    int pre = 0, all = 0;
    for (int e = tid * 4; e < T; e += BLK * 4) {
        const int4 mv = *reinterpret_cast<const int4*>(mrow + e);
        const int t0 = (mv.x != 0), t1 = (mv.y != 0), t2 = (mv.z != 0), t3 = (mv.w != 0);
        all += t0 + t1 + t2 + t3;
        if (e + 3 < j0) {
            pre += t0 + t1 + t2 + t3;
        } else if (e < j0) {
            pre += t0;
            pre += (e + 1 < j0) ? t1 : 0;
            pre += (e + 2 < j0) ? t2 : 0;
            pre += (e + 3 < j0) ? t3 : 0;
        }
    }
    unsigned long long packed =
        (unsigned long long)pre | ((unsigned long long)all << 32);
    #pragma unroll
    for (int off = 32; off; off >>= 1) packed += __shfl_xor(packed, off);

    __shared__ unsigned long long wred[NW];
    __shared__ int selRows[ROWS];
    __shared__ int nsel;
    if (lane == 0) wred[wave] = packed;
    __syncthreads();

    unsigned long long tot = 0;
    #pragma unroll
    for (int w = 0; w < NW; ++w) tot += wred[w];
    const int P = (int)(tot & 0xffffffffull);  // output base row for this chunk
    const int L = (int)(tot >> 32);            // lens[b]

    // ---- wave 0: compact selected rows of this chunk into a list ----
    if (wave == 0) {
        const int m = (mrow[j0 + lane] != 0);
        int incl = m;
        #pragma unroll
        for (int off = 1; off < 64; off <<= 1) {
            const int v = __shfl_up(incl, off);
            if (lane >= off) incl += v;
        }
        if (m) selRows[incl - 1] = lane;
        if (lane == 63) nsel = incl;
    }
    __syncthreads();
    const int n = nsel;

    if (c == 0 && tid == 0) lens_f[b] = (float)L;

    const float4* xrow = reinterpret_cast<const float4*>(x) +
                         ((size_t)b * T + j0) * (size_t)D4;
    float4* obase = reinterpret_cast<float4*>(out) + (size_t)b * T * (size_t)D4;
    const float4 z = make_float4(0.f, 0.f, 0.f, 0.f);

    // ---- copy selected rows, 2-unrolled (two independent loads, two stores) ----
    for (int i = wave; i < n; i += 2 * NW) {
        const int i2 = i + NW;
        const bool h2 = (i2 < n);
        const int r0 = selRows[i];
        const int r1 = h2 ? selRows[i2] : 0;
        for (int t = lane; t < D4; t += 64) {
            const float4 v0 = xrow[(size_t)r0 * D4 + t];
            float4 v1 = z;
            if (h2) v1 = xrow[(size_t)r1 * D4 + t];
            obase[(size_t)(P + i) * D4 + t] = v0;
            if (h2) obase[(size_t)(P + i2) * D4 + t] = v1;
        }
    }

    // ---- zero-pad rows >= L within this chunk's output range ----
    const int zstart = (L > j0) ? L : j0;
    for (int j = zstart + wave; j < j0 + ROWS; j += NW) {
        for (int t = lane; t < D4; t += 64)
            obase[(size_t)j * D4 + t] = z;
    }
}

extern "C" void kernel_launch(void* const* d_in, const int* in_sizes, int n_in,
                              void* d_out, int out_size, void* d_ws, size_t ws_size,
                              hipStream_t stream) {
    const float* x = (const float*)d_in[0];
    const int* mask = (const int*)d_in[1];

    const int Nx = in_sizes[0];   // B*T*D
    const int BT = in_sizes[1];   // B*T
    const int B = out_size - Nx;  // lens appended after x_
    const int T = BT / B;
    const int D = Nx / BT;
    const int D4 = D / 4;

    float* out = (float*)d_out;
    float* lens_f = out + (size_t)Nx;

    dim3 grid(T / ROWS, B);
    pad_masked_fused<<<grid, BLK, 0, stream>>>(x, mask, out, lens_f, T, D4);
}